// Round 5
// baseline (23.321 us; speedup 1.0000x reference)
//
#include <hip/hip_runtime.h>

#define NPTS 512
#define DIM 128
#define MARGIN 0.2f
#define ATILE 2
#define NBLK (NPTS / ATILE)     // 256 blocks = 1 per CU
#define TROWS 128               // rows per stage tile
#define NTILE (NPTS / TROWS)    // 4 tiles

// Direct global->LDS async copy, 16B per lane. LDS dest is wave-uniform base
// + lane*16 (linear); swizzle is applied by permuting the SOURCE address and
// mirroring it on the LDS read side (both-sides rule).
__device__ __forceinline__ void gload_lds16(const float4* src, float4* dst) {
    __builtin_amdgcn_global_load_lds(
        (const __attribute__((address_space(1))) void*)src,
        (__attribute__((address_space(3))) void*)dst, 16, 0, 0);
}

__global__ __launch_bounds__(512) void triplet_fused_kernel(
    const float* __restrict__ z, const int* __restrict__ labels,
    float* __restrict__ psum, unsigned* __restrict__ pcnt,
    unsigned* __restrict__ pntrip, unsigned* __restrict__ counter,
    float* __restrict__ out)
{
    __shared__ float4 stage[2][TROWS * 32];              // 128 KB double buffer
    __shared__ float part[4][TROWS][2];                  // 4 KB
    __shared__ float drow[ATILE][NPTS];                  // 4 KB
    __shared__ __align__(16) float pdm[ATILE][NPTS];     // 4 KB
    __shared__ int wcnt[ATILE][8];
    __shared__ float red_f[8];
    __shared__ unsigned red_c[8], red_n[8];
    __shared__ unsigned lastFlag;

    const int t = threadIdx.x;
    const int b = blockIdx.x;
    const int a0 = b * ATILE;
    const int wid = t >> 6, lane = t & 63;
    const int q = t >> 7;                 // k-quarter (wave-uniform)
    const int r = t & (TROWS - 1);        // row within tile
    const int lane5 = lane & 31;
    const int lh = lane >> 5;

    const float4* zg = reinterpret_cast<const float4*>(z);

    // Early independent loads (drained by first barrier).
    const int lt = labels[t];
    int la[ATILE];
    #pragma unroll
    for (int i = 0; i < ATILE; ++i) la[i] = labels[a0 + i];

    float4 za[ATILE][8];                  // anchor rows, own k-quarter
    #pragma unroll
    for (int i = 0; i < ATILE; ++i)
        #pragma unroll
        for (int kk = 0; kk < 8; ++kk)
            za[i][kk] = zg[(size_t)(a0 + i) * 32 + q * 8 + kk];

    // Stage tile 0 (8 x global_load_lds per wave; source pre-swizzled).
    #pragma unroll
    for (int p = 0; p < 8; ++p) {
        int row = (wid << 4) + (p << 1) + lh;
        int srcu = row * 32 + (lane5 ^ (row & 7));
        gload_lds16(zg + srcu, &stage[0][(wid << 9) + (p << 6)]);
    }
    __syncthreads();                      // drains vmcnt -> buf0 ready

    const int rx = r & 7;
    for (int T = 0; T < NTILE; ++T) {
        const int cur = T & 1;
        if (T + 1 < NTILE) {              // issue next tile before computing
            #pragma unroll
            for (int p = 0; p < 8; ++p) {
                int row = (wid << 4) + (p << 1) + lh;
                int srcu = ((T + 1) * TROWS + row) * 32 + (lane5 ^ (row & 7));
                gload_lds16(zg + srcu, &stage[cur ^ 1][(wid << 9) + (p << 6)]);
            }
        }
        float acc0 = 0.f, acc1 = 0.f;
        #pragma unroll
        for (int kk = 0; kk < 8; ++kk) {
            float4 v = stage[cur][r * 32 + ((q * 8 + kk) ^ rx)];
            float4 w0 = za[0][kk], w1 = za[1][kk];
            float d0 = w0.x - v.x, d1 = w0.y - v.y, d2 = w0.z - v.z, d3 = w0.w - v.w;
            acc0 += d0 * d0 + d1 * d1 + d2 * d2 + d3 * d3;
            float e0 = w1.x - v.x, e1 = w1.y - v.y, e2 = w1.z - v.z, e3 = w1.w - v.w;
            acc1 += e0 * e0 + e1 * e1 + e2 * e2 + e3 * e3;
        }
        part[q][r][0] = acc0;
        part[q][r][1] = acc1;
        __syncthreads();                  // part ready; next-tile loads drained
        if (t < 2 * TROWS) {
            int rr = t & (TROWS - 1), ii = t >> 7;
            float s = part[0][rr][ii] + part[1][rr][ii]
                    + part[2][rr][ii] + part[3][rr][ii];
            drow[ii][T * TROWS + rr] = sqrtf(s);
        }
        __syncthreads();                  // part consumable again
    }

    // ---- compact positives per anchor (deterministic order) ----
    bool pred[ATILE];
    unsigned long long m[ATILE];
    #pragma unroll
    for (int i = 0; i < ATILE; ++i) {
        pred[i] = (lt == la[i]) && (t != a0 + i);
        m[i] = __ballot(pred[i]);
        if (lane == 0) wcnt[i][wid] = (int)__popcll(m[i]);
    }
    __syncthreads();

    unsigned np[ATILE], npad[ATILE];
    #pragma unroll
    for (int i = 0; i < ATILE; ++i) {
        unsigned base = 0, n = 0;
        #pragma unroll
        for (int w = 0; w < 8; ++w) {
            unsigned c = (unsigned)wcnt[i][w];
            if (w < wid) base += c;
            n += c;
        }
        np[i] = n;
        npad[i] = (n + 3u) & ~3u;
        if (pred[i])
            pdm[i][base + __popcll(m[i] & ((1ull << lane) - 1ull))] = drow[i][t] + MARGIN;
        if ((unsigned)t >= n && (unsigned)t < npad[i])
            pdm[i][t] = -1e30f;           // padding never fires relu
    }
    __syncthreads();

    // ---- accumulate: thread t = negative candidate t ----
    float sum = 0.f;
    unsigned cnt = 0;
    #pragma unroll
    for (int i = 0; i < ATILE; ++i) {
        if (lt != la[i]) {
            const float si = drow[i][t];
            const float4* p4 = reinterpret_cast<const float4*>(pdm[i]);
            const int n4 = (int)(npad[i] >> 2);
            for (int p = 0; p < n4; ++p) {
                float4 qv = p4[p];        // LDS broadcast
                float v0 = qv.x - si, v1 = qv.y - si, v2 = qv.z - si, v3 = qv.w - si;
                if (v0 > 0.f) { sum += v0; ++cnt; }
                if (v1 > 0.f) { sum += v1; ++cnt; }
                if (v2 > 0.f) { sum += v2; ++cnt; }
                if (v3 > 0.f) { sum += v3; ++cnt; }
            }
        }
    }

    // ---- block reduction ----
    #pragma unroll
    for (int off = 32; off > 0; off >>= 1) {
        sum += __shfl_down(sum, off, 64);
        cnt += __shfl_down(cnt, off, 64);
    }
    if (lane == 0) { red_f[wid] = sum; red_c[wid] = cnt; }
    __syncthreads();

    if (t == 0) {
        float S = 0.f;
        unsigned C = 0;
        #pragma unroll
        for (int w = 0; w < 8; ++w) { S += red_f[w]; C += red_c[w]; }
        unsigned NT = 0;
        #pragma unroll
        for (int i = 0; i < ATILE; ++i) NT += np[i] * (unsigned)(NPTS - 1 - np[i]);
        // publish partials with agent scope, then arrive.
        __hip_atomic_store(&psum[b], S, __ATOMIC_RELAXED, __HIP_MEMORY_SCOPE_AGENT);
        __hip_atomic_store(&pcnt[b], C, __ATOMIC_RELAXED, __HIP_MEMORY_SCOPE_AGENT);
        __hip_atomic_store(&pntrip[b], NT, __ATOMIC_RELAXED, __HIP_MEMORY_SCOPE_AGENT);
        unsigned old = __hip_atomic_fetch_add(counter, 1u, __ATOMIC_ACQ_REL,
                                              __HIP_MEMORY_SCOPE_AGENT);
        lastFlag = (old == NBLK - 1) ? 1u : 0u;
    }
    __syncthreads();

    // ---- last block: final deterministic reduction ----
    if (lastFlag) {
        float s = 0.f;
        unsigned c = 0, nt = 0;
        if (t < NBLK) {
            s  = __hip_atomic_load(&psum[t],   __ATOMIC_RELAXED, __HIP_MEMORY_SCOPE_AGENT);
            c  = __hip_atomic_load(&pcnt[t],   __ATOMIC_RELAXED, __HIP_MEMORY_SCOPE_AGENT);
            nt = __hip_atomic_load(&pntrip[t], __ATOMIC_RELAXED, __HIP_MEMORY_SCOPE_AGENT);
        }
        #pragma unroll
        for (int off = 32; off > 0; off >>= 1) {
            s  += __shfl_down(s,  off, 64);
            c  += __shfl_down(c,  off, 64);
            nt += __shfl_down(nt, off, 64);
        }
        if (lane == 0) { red_f[wid] = s; red_c[wid] = c; red_n[wid] = nt; }
        __syncthreads();
        if (t == 0) {
            double S = 0.0;
            unsigned C = 0, NT = 0;
            #pragma unroll
            for (int w = 0; w < 4; ++w) {   // blocks 0..255 live in waves 0..3
                S += (double)red_f[w]; C += red_c[w]; NT += red_n[w];
            }
            out[0] = (float)(S / (double)NT);
            out[1] = (float)C;
        }
    }
}

extern "C" void kernel_launch(void* const* d_in, const int* in_sizes, int n_in,
                              void* d_out, int out_size, void* d_ws, size_t ws_size,
                              hipStream_t stream) {
    const float* z = (const float*)d_in[0];
    const int* labels = (const int*)d_in[1];
    float* out = (float*)d_out;

    unsigned* counter = (unsigned*)d_ws;
    float* psum = (float*)((char*)d_ws + 16);
    unsigned* pcnt = (unsigned*)((char*)d_ws + 16 + NBLK * 4);
    unsigned* pntrip = (unsigned*)((char*)d_ws + 16 + NBLK * 8);

    hipMemsetAsync(counter, 0, sizeof(unsigned), stream);   // capture-safe node
    triplet_fused_kernel<<<NBLK, 512, 0, stream>>>(z, labels, psum, pcnt, pntrip,
                                                   counter, out);
}

// Round 6
// 19.693 us; speedup vs baseline: 1.1843x; 1.1843x over previous
//
#include <hip/hip_runtime.h>

#define NPTS 512
#define DIM 128
#define MARGIN 0.2f
#define ATILE 2
#define NBLK (NPTS / ATILE)     // 256 blocks = 1 per CU
#define TROWS 256               // rows per stage tile
#define NTILE (NPTS / TROWS)    // 2 tiles
#define NTHR 1024

// Fused: per-block partials + modular last-arrival final reduction.
// Counter is never reset: each call adds exactly NBLK, so exactly one block
// sees (old & (NBLK-1)) == NBLK-1 per call, for ANY starting value.
__global__ __launch_bounds__(NTHR) void triplet_fused_kernel(
    const float* __restrict__ z, const int* __restrict__ labels,
    float* __restrict__ psum, unsigned* __restrict__ pcnt,
    unsigned* __restrict__ pntrip, unsigned* __restrict__ counter,
    float* __restrict__ out)
{
    __shared__ float4 stage[TROWS * 32];                 // 128 KB
    __shared__ float part[4][TROWS][ATILE];              // 8 KB
    __shared__ float drow[ATILE][NPTS];                  // 4 KB
    __shared__ __align__(16) float pdm[ATILE][NPTS];     // 4 KB
    __shared__ int wcnt[16];
    __shared__ float red_f[16];
    __shared__ unsigned red_c[16], red_n[16];
    __shared__ unsigned lastFlag;

    const int t = threadIdx.x;
    const int b = blockIdx.x;
    const int a0 = b * ATILE;
    const int wid = t >> 6, lane = t & 63;
    const int q = t >> 8;              // k-quarter (wave-uniform)
    const int r = t & (TROWS - 1);     // row within stage tile
    const int c = t & (NPTS - 1);      // candidate id (phases 2-3)
    const int ai = t >> 9;             // anchor id (phases 2-3)

    const float4* zg = reinterpret_cast<const float4*>(z);

    const int lc = labels[c];          // own candidate label (coalesced)
    int la[ATILE];
    #pragma unroll
    for (int i = 0; i < ATILE; ++i) la[i] = labels[a0 + i];  // uniform

    float4 za[ATILE][8];               // anchor rows, own k-quarter
    #pragma unroll
    for (int i = 0; i < ATILE; ++i)
        #pragma unroll
        for (int kk = 0; kk < 8; ++kk)
            za[i][kk] = zg[(size_t)(a0 + i) * 32 + q * 8 + kk];

    // ---- distance phase: 2 tiles of 256 rows ----
    const int rx = r & 7;
    for (int T = 0; T < NTILE; ++T) {
        #pragma unroll
        for (int p = 0; p < 8; ++p) {              // coalesced reg-staging
            int f = p * NTHR + t;                  // 0..8191
            int row = f >> 5, ch = f & 31;
            float4 v = zg[(size_t)(T * TROWS + row) * 32 + ch];
            stage[row * 32 + (ch ^ (row & 7))] = v;   // both-sides swizzle
        }
        __syncthreads();                           // stage ready (also: part free)

        float acc0 = 0.f, acc1 = 0.f;
        #pragma unroll
        for (int kk = 0; kk < 8; ++kk) {
            float4 v = stage[r * 32 + ((q * 8 + kk) ^ rx)];   // conflict-free
            float4 w0 = za[0][kk], w1 = za[1][kk];
            float d0 = w0.x - v.x, d1 = w0.y - v.y, d2 = w0.z - v.z, d3 = w0.w - v.w;
            acc0 += d0 * d0 + d1 * d1 + d2 * d2 + d3 * d3;
            float e0 = w1.x - v.x, e1 = w1.y - v.y, e2 = w1.z - v.z, e3 = w1.w - v.w;
            acc1 += e0 * e0 + e1 * e1 + e2 * e2 + e3 * e3;
        }
        part[q][r][0] = acc0;
        part[q][r][1] = acc1;
        __syncthreads();                           // part ready; stage reads done

        if (t < 2 * TROWS) {                       // 512 threads do sqrt
            int rr = t & (TROWS - 1), ii = t >> 8; // ii in {0,1}
            float s = part[0][rr][ii] + part[1][rr][ii]
                    + part[2][rr][ii] + part[3][rr][ii];
            drow[ii][T * TROWS + rr] = sqrtf(s);
        }
        __syncthreads();                           // part consumable; drow visible
    }

    // ---- compaction: waves 0-7 -> anchor 0, waves 8-15 -> anchor 1 ----
    const bool pred = (lc == la[ai]) && (c != a0 + ai);
    const unsigned long long m = __ballot(pred);
    if (lane == 0) wcnt[wid] = (int)__popcll(m);
    __syncthreads();

    unsigned base = 0, np = 0;
    #pragma unroll
    for (int w = 0; w < 8; ++w) {
        unsigned cw = (unsigned)wcnt[ai * 8 + w];
        if (ai * 8 + w < wid) base += cw;
        np += cw;
    }
    const unsigned npad = (np + 3u) & ~3u;
    if (pred)
        pdm[ai][base + __popcll(m & ((1ull << lane) - 1ull))] = drow[ai][c] + MARGIN;
    if ((unsigned)c >= np && (unsigned)c < npad)
        pdm[ai][c] = -1e30f;                       // padding never fires relu
    __syncthreads();

    // ---- accumulate: thread = (anchor ai, negative c) ----
    float sum = 0.f;
    unsigned cnt = 0;
    if (lc != la[ai]) {
        const float si = drow[ai][c];
        const float4* p4 = reinterpret_cast<const float4*>(pdm[ai]);
        const int n4 = (int)(npad >> 2);           // wave-uniform
        for (int p = 0; p < n4; ++p) {
            float4 qv = p4[p];                     // LDS broadcast
            float v0 = qv.x - si, v1 = qv.y - si, v2 = qv.z - si, v3 = qv.w - si;
            if (v0 > 0.f) { sum += v0; ++cnt; }
            if (v1 > 0.f) { sum += v1; ++cnt; }
            if (v2 > 0.f) { sum += v2; ++cnt; }
            if (v3 > 0.f) { sum += v3; ++cnt; }
        }
    }

    // ---- block reduction over 16 waves ----
    #pragma unroll
    for (int off = 32; off > 0; off >>= 1) {
        sum += __shfl_down(sum, off, 64);
        cnt += __shfl_down(cnt, off, 64);
    }
    if (lane == 0) { red_f[wid] = sum; red_c[wid] = cnt; }
    __syncthreads();

    if (t == 0) {
        float S = 0.f;
        unsigned C = 0;
        #pragma unroll
        for (int w = 0; w < 16; ++w) { S += red_f[w]; C += red_c[w]; }
        unsigned np0 = 0, np1 = 0;
        #pragma unroll
        for (int w = 0; w < 8; ++w) { np0 += (unsigned)wcnt[w]; np1 += (unsigned)wcnt[8 + w]; }
        unsigned NT = np0 * (NPTS - 1 - np0) + np1 * (NPTS - 1 - np1);
        psum[b] = S;
        pcnt[b] = C;
        pntrip[b] = NT;
        // release partials via the RMW; last arrival (mod NBLK) finalizes.
        unsigned old = __hip_atomic_fetch_add(counter, 1u, __ATOMIC_ACQ_REL,
                                              __HIP_MEMORY_SCOPE_AGENT);
        lastFlag = ((old & (NBLK - 1u)) == NBLK - 1u) ? 1u : 0u;
    }
    __syncthreads();

    // ---- last-arrival block: final deterministic reduction ----
    if (lastFlag) {
        float s = 0.f;
        unsigned cc = 0, nt = 0;
        if (t < NBLK) {
            s  = __hip_atomic_load(&psum[t],   __ATOMIC_RELAXED, __HIP_MEMORY_SCOPE_AGENT);
            cc = __hip_atomic_load(&pcnt[t],   __ATOMIC_RELAXED, __HIP_MEMORY_SCOPE_AGENT);
            nt = __hip_atomic_load(&pntrip[t], __ATOMIC_RELAXED, __HIP_MEMORY_SCOPE_AGENT);
        }
        #pragma unroll
        for (int off = 32; off > 0; off >>= 1) {
            s  += __shfl_down(s,  off, 64);
            cc += __shfl_down(cc, off, 64);
            nt += __shfl_down(nt, off, 64);
        }
        if (lane == 0) { red_f[wid] = s; red_c[wid] = cc; red_n[wid] = nt; }
        __syncthreads();
        if (t == 0) {
            double S = 0.0;
            unsigned C = 0, NT = 0;
            #pragma unroll
            for (int w = 0; w < 4; ++w) {   // entries 0..255 live in waves 0..3
                S += (double)red_f[w]; C += red_c[w]; NT += red_n[w];
            }
            out[0] = (float)(S / (double)NT);
            out[1] = (float)C;
        }
    }
}

extern "C" void kernel_launch(void* const* d_in, const int* in_sizes, int n_in,
                              void* d_out, int out_size, void* d_ws, size_t ws_size,
                              hipStream_t stream) {
    const float* z = (const float*)d_in[0];
    const int* labels = (const int*)d_in[1];
    float* out = (float*)d_out;

    unsigned* counter = (unsigned*)d_ws;
    float* psum = (float*)((char*)d_ws + 16);
    unsigned* pcnt = (unsigned*)((char*)d_ws + 16 + NBLK * 4);
    unsigned* pntrip = (unsigned*)((char*)d_ws + 16 + NBLK * 8);

    triplet_fused_kernel<<<NBLK, NTHR, 0, stream>>>(z, labels, psum, pcnt, pntrip,
                                                    counter, out);
}

// Round 7
// 16.834 us; speedup vs baseline: 1.3854x; 1.1698x over previous
//
#include <hip/hip_runtime.h>

#define NPTS 512
#define DIM 128
#define MARGIN 0.2f
#define TROWS 64
#define NTILE (NPTS / TROWS)    // 8 tiles
#define NTHR 512
#define NBLK NPTS               // 512 blocks = 2 per CU

// One block per anchor. z staged through a double-buffered 2x32KB LDS tile
// (reg-staged: global->reg issued before compute, reg->LDS after).
// Thread t = (row r = t>>3, k-eighth q = t&7); 3 shfl_xor reduce the k-split.
__global__ __launch_bounds__(NTHR, 4) void triplet_partial_kernel(
    const float* __restrict__ z, const int* __restrict__ labels,
    float* __restrict__ psum, unsigned* __restrict__ pcnt,
    unsigned* __restrict__ pntrip)
{
    __shared__ float4 stage[2][TROWS * 32];          // 64 KB
    __shared__ float drow[NPTS];                     // 2 KB
    __shared__ __align__(16) float pdm[NPTS];        // 2 KB
    __shared__ int wcnt[8];
    __shared__ float red_f[8];
    __shared__ unsigned red_c[8];

    const int t = threadIdx.x;
    const int a = blockIdx.x;
    const int wid = t >> 6, lane = t & 63;
    const int r = t >> 3;          // row within tile (0..63)
    const int q = t & 7;           // k-eighth
    const int rx = r & 7;

    const float4* zg = reinterpret_cast<const float4*>(z);

    const int lt = labels[t];      // coalesced (own candidate label)
    const int la = labels[a];      // uniform s_load

    float4 za[4];                  // anchor row, own k-eighth (4 float4)
    #pragma unroll
    for (int kk = 0; kk < 4; ++kk)
        za[kk] = zg[(size_t)a * 32 + q * 4 + kk];

    // prologue: stage tile 0 (coalesced, both-sides XOR swizzle)
    #pragma unroll
    for (int p = 0; p < 4; ++p) {
        int f = p * NTHR + t;                  // 0..2047
        int row = f >> 5, ch = f & 31;
        stage[0][row * 32 + (ch ^ (row & 7))] = zg[f];
    }
    __syncthreads();

    for (int T = 0; T < NTILE; ++T) {
        const int cur = T & 1;
        float4 pf[4];
        if (T + 1 < NTILE) {                   // issue next tile's loads early
            #pragma unroll
            for (int p = 0; p < 4; ++p)
                pf[p] = zg[(size_t)(T + 1) * (TROWS * 32) + p * NTHR + t];
        }
        // compute current tile from LDS (conflict-balanced reads)
        float acc = 0.f;
        #pragma unroll
        for (int kk = 0; kk < 4; ++kk) {
            float4 v = stage[cur][r * 32 + ((q * 4 + kk) ^ rx)];
            float4 w = za[kk];
            float d0 = w.x - v.x, d1 = w.y - v.y, d2 = w.z - v.z, d3 = w.w - v.w;
            acc += d0 * d0 + d1 * d1 + d2 * d2 + d3 * d3;
        }
        acc += __shfl_xor(acc, 1, 64);         // reduce k-eighths (lane bits 0-2)
        acc += __shfl_xor(acc, 2, 64);
        acc += __shfl_xor(acc, 4, 64);
        if (q == 0) drow[T * TROWS + r] = sqrtf(acc);
        if (T + 1 < NTILE) {                   // write-late (vmcnt drained here)
            #pragma unroll
            for (int p = 0; p < 4; ++p) {
                int f = p * NTHR + t;
                int row = f >> 5, ch = f & 31;
                stage[cur ^ 1][row * 32 + (ch ^ (row & 7))] = pf[p];
            }
        }
        __syncthreads();                       // one barrier per tile
    }

    // ---- compact positives (deterministic order) ----
    const bool pred = (lt == la) && (t != a);
    const unsigned long long m = __ballot(pred);
    if (lane == 0) wcnt[wid] = (int)__popcll(m);
    __syncthreads();

    unsigned base = 0, np = 0;
    #pragma unroll
    for (int w = 0; w < 8; ++w) {
        unsigned cw = (unsigned)wcnt[w];
        if (w < wid) base += cw;
        np += cw;
    }
    const unsigned npad = (np + 3u) & ~3u;
    if (pred)
        pdm[base + __popcll(m & ((1ull << lane) - 1ull))] = drow[t] + MARGIN;
    if ((unsigned)t >= np && (unsigned)t < npad)
        pdm[t] = -1e30f;                       // padding never fires relu
    __syncthreads();

    // ---- accumulate: thread t = negative candidate t ----
    float sum = 0.f;
    unsigned cnt = 0;
    if (lt != la) {
        const float si = drow[t];
        const float4* p4 = reinterpret_cast<const float4*>(pdm);
        const int n4 = (int)(npad >> 2);       // block-uniform, ~2-6 iters
        for (int p = 0; p < n4; ++p) {
            float4 qv = p4[p];                 // LDS broadcast
            float v0 = qv.x - si, v1 = qv.y - si, v2 = qv.z - si, v3 = qv.w - si;
            if (v0 > 0.f) { sum += v0; ++cnt; }
            if (v1 > 0.f) { sum += v1; ++cnt; }
            if (v2 > 0.f) { sum += v2; ++cnt; }
            if (v3 > 0.f) { sum += v3; ++cnt; }
        }
    }

    // ---- block reduction ----
    #pragma unroll
    for (int off = 32; off > 0; off >>= 1) {
        sum += __shfl_down(sum, off, 64);
        cnt += __shfl_down(cnt, off, 64);
    }
    if (lane == 0) { red_f[wid] = sum; red_c[wid] = cnt; }
    __syncthreads();
    if (t == 0) {
        float S = 0.f;
        unsigned C = 0;
        #pragma unroll
        for (int w = 0; w < 8; ++w) { S += red_f[w]; C += red_c[w]; }
        psum[a] = S;
        pcnt[a] = C;
        pntrip[a] = np * (unsigned)(NPTS - 1 - np);
    }
}

// Deterministic reduction of the 512 per-anchor partials.
__global__ __launch_bounds__(512) void triplet_final_kernel(
    const float* __restrict__ psum, const unsigned* __restrict__ pcnt,
    const unsigned* __restrict__ pntrip, float* __restrict__ out)
{
    __shared__ float rf[8];
    __shared__ unsigned rc[8], rn[8];

    const int t = threadIdx.x;
    float s = psum[t];
    unsigned c = pcnt[t];
    unsigned nt = pntrip[t];

    #pragma unroll
    for (int off = 32; off > 0; off >>= 1) {
        s  += __shfl_down(s,  off, 64);
        c  += __shfl_down(c,  off, 64);
        nt += __shfl_down(nt, off, 64);
    }
    const int wid = t >> 6, lane = t & 63;
    if (lane == 0) { rf[wid] = s; rc[wid] = c; rn[wid] = nt; }
    __syncthreads();
    if (t == 0) {
        double S = 0.0;
        unsigned C = 0, NT = 0;
        #pragma unroll
        for (int w = 0; w < 8; ++w) { S += (double)rf[w]; C += rc[w]; NT += rn[w]; }
        out[0] = (float)(S / (double)NT);
        out[1] = (float)C;
    }
}

extern "C" void kernel_launch(void* const* d_in, const int* in_sizes, int n_in,
                              void* d_out, int out_size, void* d_ws, size_t ws_size,
                              hipStream_t stream) {
    const float* z = (const float*)d_in[0];
    const int* labels = (const int*)d_in[1];
    float* out = (float*)d_out;

    float* psum = (float*)d_ws;
    unsigned* pcnt = (unsigned*)((char*)d_ws + NBLK * sizeof(float));
    unsigned* pntrip = pcnt + NBLK;

    triplet_partial_kernel<<<NBLK, NTHR, 0, stream>>>(z, labels, psum, pcnt, pntrip);
    triplet_final_kernel<<<1, NPTS, 0, stream>>>(psum, pcnt, pntrip, out);
}